// Round 9
// baseline (59.575 us; speedup 1.0000x reference)
//
#include <hip/hip_runtime.h>

#define BB 8
#define LL 32768
#define DD 64

typedef float f4 __attribute__((ext_vector_type(4)));
typedef unsigned long long u64x2 __attribute__((ext_vector_type(2)));

// ws layout:
// [0, 512K)            : double part[BB][128][DD] partial q-sums (fully written by k1)
// [512K, 512K+BB*LL*8) : double scores[BB*LL]  (2 MiB, fully written by k2)

#define OUT_F4 (BB * LL * DD / 4)  // 4,194,304 float4s in out
#define CHUNKS_Q 128               // blocks per batch in k_reduce_q
#define ROWS_Q (LL / CHUNKS_Q)     // 256 rows per block

// ---------------- Kernel 1: per-chunk partials of sum_l relu(q)+eps ----------------
// 1024 blocks x 256 threads; 16-deep load batch for MLP. Zero-fills first half of out.
__global__ __launch_bounds__(256) void k_reduce_q(const float* __restrict__ q,
                                                  double* __restrict__ part,
                                                  float* __restrict__ out) {
    int b     = blockIdx.x >> 7;           // /CHUNKS_Q
    int chunk = blockIdx.x & (CHUNKS_Q - 1);
    int quad  = threadIdx.x & 15;          // which float4 of the 64-wide row
    int rowg  = threadIdx.x >> 4;          // 16 row-groups

    const f4* qb = (const f4*)(q + (size_t)b * LL * DD);
    const f4* base = qb + (size_t)(chunk * ROWS_Q + rowg) * 16 + quad;

    // issue ALL 16 row loads first (16 deep in flight)
    f4 vb[16];
#pragma unroll
    for (int j = 0; j < 16; ++j)
        vb[j] = base[(size_t)j * 256];     // 16 rows = 256 f4 stride

    // zero-fill rides in the load shadow (stores don't stall)
    {
        f4 z = (f4)(0.0f);
        f4* oz = (f4*)out + (size_t)blockIdx.x * 2048 + threadIdx.x;
#pragma unroll
        for (int i = 0; i < 8; ++i) oz[i * 256] = z;
    }

    double a0 = 0.0, a1 = 0.0, a2 = 0.0, a3 = 0.0;
#pragma unroll
    for (int j = 0; j < 16; ++j) {
        a0 += (double)fmaxf(vb[j].x, 0.0f) + 1e-3;
        a1 += (double)fmaxf(vb[j].y, 0.0f) + 1e-3;
        a2 += (double)fmaxf(vb[j].z, 0.0f) + 1e-3;
        a3 += (double)fmaxf(vb[j].w, 0.0f) + 1e-3;
    }

    __shared__ double lds[16][16][5];   // [5] pads away bank conflicts
    lds[rowg][quad][0] = a0; lds[rowg][quad][1] = a1;
    lds[rowg][quad][2] = a2; lds[rowg][quad][3] = a3;
    __syncthreads();
    for (int s = 8; s > 0; s >>= 1) {
        if (rowg < s) {
            lds[rowg][quad][0] += lds[rowg + s][quad][0];
            lds[rowg][quad][1] += lds[rowg + s][quad][1];
            lds[rowg][quad][2] += lds[rowg + s][quad][2];
            lds[rowg][quad][3] += lds[rowg + s][quad][3];
        }
        __syncthreads();
    }
    if (rowg == 0) {
        double* pp = part + ((size_t)b * CHUNKS_Q + chunk) * DD;
        pp[quad * 4 + 0] = lds[0][quad][0];
        pp[quad * 4 + 1] = lds[0][quad][1];
        pp[quad * 4 + 2] = lds[0][quad][2];
        pp[quad * 4 + 3] = lds[0][quad][3];
    }
}

// ---------------- Kernel 2: reduce partials -> rq, then scores ----------------
// 1024 blocks x 256 threads, 256 rows each; 16-deep load batch.
// Zero-fills the SECOND half of out.
__global__ __launch_bounds__(256) void k_scores(const float* __restrict__ k,
                                                const double* __restrict__ part,
                                                double* __restrict__ scores,
                                                float* __restrict__ out) {
    const int RPB = 256;
    int b     = blockIdx.x >> 7;          // /(LL/RPB)
    int chunk = blockIdx.x & 127;
    int sub   = threadIdx.x & 15;
    int rowIn = threadIdx.x >> 4;

    const f4* kb = (const f4*)(k + (size_t)b * LL * DD);
    int l0 = chunk * RPB;
    const f4* base = kb + (size_t)(l0 + rowIn) * 16 + sub;

    // issue the 16 main K-row loads FIRST (in flight across the whole preamble)
    f4 vb[16];
#pragma unroll
    for (int j = 0; j < 16; ++j)
        vb[j] = base[(size_t)j * 256];

    // zero-fill in the load shadow
    {
        f4 z = (f4)(0.0f);
        f4* oz = (f4*)out + (size_t)(OUT_F4 / 2)
               + (size_t)blockIdx.x * 2048 + threadIdx.x;
#pragma unroll
        for (int i = 0; i < 8; ++i) oz[i * 256] = z;
    }

    // reconstruct rq[b,:] from the 128 chunk-partials (L2-hot, coalesced)
    __shared__ double s_part[4][DD];
    __shared__ double s_rq[DD];
    {
        int d = threadIdx.x & 63;
        int g = threadIdx.x >> 6;   // 0..3
        const double* pp = part + (size_t)b * CHUNKS_Q * DD;
        double acc = 0.0;
#pragma unroll
        for (int j = 0; j < 32; ++j)
            acc += pp[(size_t)(g * 32 + j) * DD + d];
        s_part[g][d] = acc;
    }
    __syncthreads();
    if (threadIdx.x < DD) {
        int d = threadIdx.x;
        s_rq[d] = (s_part[0][d] + s_part[1][d]) + (s_part[2][d] + s_part[3][d]);
    }
    __syncthreads();

    double r0 = s_rq[sub * 4 + 0];
    double r1 = s_rq[sub * 4 + 1];
    double r2 = s_rq[sub * 4 + 2];
    double r3 = s_rq[sub * 4 + 3];

#pragma unroll
    for (int j = 0; j < 16; ++j) {
        double s = r0 * ((double)fmaxf(vb[j].x, 0.0f) + 1e-3)
                 + r1 * ((double)fmaxf(vb[j].y, 0.0f) + 1e-3)
                 + r2 * ((double)fmaxf(vb[j].z, 0.0f) + 1e-3)
                 + r3 * ((double)fmaxf(vb[j].w, 0.0f) + 1e-3);
        s += __shfl_xor(s, 1, 16);
        s += __shfl_xor(s, 2, 16);
        s += __shfl_xor(s, 4, 16);
        s += __shfl_xor(s, 8, 16);
        if (sub == 0)
            scores[(size_t)b * LL + l0 + rowIn + 16 * j] = s;
    }
}

// ---------------- Kernel 3: radix select + gather selected V rows ----------------
// One block per batch, 1024 threads, 32 keys/thread (16x 16B vector loads).
// Positive doubles -> uint64 bit pattern preserves ordering.
// Early exit: once the chosen radix bucket holds exactly 1 key, that key IS the cutoff.
#define NCOPY 16
#define HSTRIDE 257
#define MAXSEL 96
__global__ __launch_bounds__(1024) void k_select_gather(const double* __restrict__ scores,
                                                        const int* __restrict__ topk_p,
                                                        const float* __restrict__ v,
                                                        float* __restrict__ out) {
    const int T = 1024;
    const int KPT = LL / T;  // 32
    int b   = blockIdx.x;
    int tid = threadIdx.x;

    const u64x2* sb2 = (const u64x2*)(scores + (size_t)b * LL);

    unsigned long long key[KPT];
    unsigned long long myAnd = ~0ULL, myOr = 0ULL;
#pragma unroll
    for (int j = 0; j < KPT / 2; ++j) {
        u64x2 p = sb2[tid + j * T];
        key[2 * j]     = p.x;
        key[2 * j + 1] = p.y;
        myAnd &= p.x & p.y;
        myOr  |= p.x | p.y;
    }

    __shared__ unsigned long long sAnd[16], sOr[16];
#pragma unroll
    for (int off = 32; off >= 1; off >>= 1) {
        myAnd &= __shfl_down(myAnd, off);
        myOr  |= __shfl_down(myOr, off);
    }
    int wave = tid >> 6;
    if ((tid & 63) == 0) { sAnd[wave] = myAnd; sOr[wave] = myOr; }
    __syncthreads();
    __shared__ unsigned long long bAnd, bOr;
    if (tid == 0) {
        unsigned long long a = ~0ULL, o = 0ULL;
#pragma unroll
        for (int w = 0; w < 16; ++w) { a &= sAnd[w]; o |= sOr[w]; }
        bAnd = a; bOr = o;
    }

    __shared__ unsigned int hist[NCOPY * HSTRIDE];
    __shared__ unsigned int sTot[256];
    __shared__ unsigned long long sh_prefix;
    __shared__ int sh_r;
    __shared__ int sh_digit, sh_newr, sh_cnt, sh_done;
    if (tid == 0) { sh_prefix = 0ULL; sh_r = topk_p[0]; sh_done = 0; }
    __syncthreads();

    int copy = tid & (NCOPY - 1);

    for (int shift = 56; shift >= 0; shift -= 8) {
        if (sh_done) break;

        unsigned int dA = (unsigned int)(bAnd >> shift) & 255u;
        unsigned int dO = (unsigned int)(bOr  >> shift) & 255u;
        if (dA == dO) {
            if (tid == 0) sh_prefix |= ((unsigned long long)dA << shift);
            __syncthreads();
            continue;
        }

        for (int i = tid; i < NCOPY * HSTRIDE; i += T) hist[i] = 0;
        __syncthreads();

        unsigned long long prefix = sh_prefix;
        unsigned long long hm = (shift == 56) ? 0ULL : (~0ULL << (shift + 8));
        int r = sh_r;

#pragma unroll
        for (int i = 0; i < KPT; ++i) {
            unsigned long long kk = key[i];
            if ((kk & hm) == prefix) {
                unsigned int d = (unsigned int)(kk >> shift) & 255u;
                atomicAdd(&hist[copy * HSTRIDE + d], 1u);
            }
        }
        __syncthreads();

        if (tid < 256) {
            unsigned int t = 0;
#pragma unroll
            for (int c = 0; c < NCOPY; ++c) t += hist[c * HSTRIDE + tid];
            sTot[tid] = t;
        }
        __syncthreads();

        for (int s = 1; s < 256; s <<= 1) {
            unsigned int vv = 0;
            if (tid < 256 && tid + s < 256) vv = sTot[tid + s];
            __syncthreads();
            if (tid < 256) sTot[tid] += vv;
            __syncthreads();
        }

        if (tid < 256) {
            unsigned int suf  = sTot[tid];
            unsigned int sufn = (tid == 255) ? 0u : sTot[tid + 1];
            if (suf > (unsigned int)r && sufn <= (unsigned int)r) {
                sh_digit = tid;
                sh_newr  = r - (int)sufn;
                sh_cnt   = (int)(suf - sufn);
            }
        }
        __syncthreads();
        if (tid == 0) {
            sh_prefix |= ((unsigned long long)sh_digit << shift);
            sh_r = sh_newr;
        }
        __syncthreads();

        if (sh_cnt == 1 && shift > 0) {
            unsigned long long pfx = sh_prefix;
            unsigned long long hm2 = ~0ULL << shift;
#pragma unroll
            for (int i = 0; i < KPT; ++i) {
                if ((key[i] & hm2) == pfx) {
                    sh_prefix = key[i];   // unique owner
                    sh_done = 1;
                }
            }
        }
        __syncthreads();
    }

    // ---- gather phase: rows with key > cutoff get V copied into out ----
    __shared__ int s_cnt;
    __shared__ int s_idx[MAXSEL];
    if (tid == 0) s_cnt = 0;
    __syncthreads();
    unsigned long long cb = sh_prefix;
#pragma unroll
    for (int i = 0; i < KPT; ++i) {
        if (key[i] > cb) {
            int slot = atomicAdd(&s_cnt, 1);
            if (slot < MAXSEL)
                s_idx[slot] = 2 * (tid + (i >> 1) * T) + (i & 1);
        }
    }
    __syncthreads();
    int cnt = s_cnt < MAXSEL ? s_cnt : MAXSEL;

    int g      = tid >> 4;   // 64 groups of 16 lanes
    int lane16 = tid & 15;
    for (int r = g; r < cnt; r += 64) {
        size_t rowOff = ((size_t)b * LL + s_idx[r]) * DD;
        const f4* vrow = (const f4*)(v + rowOff);
        f4*       orow = (f4*)(out + rowOff);
        orow[lane16] = vrow[lane16];
    }
}

extern "C" void kernel_launch(void* const* d_in, const int* in_sizes, int n_in,
                              void* d_out, int out_size, void* d_ws, size_t ws_size,
                              hipStream_t stream) {
    const float* q = (const float*)d_in[0];
    const float* k = (const float*)d_in[1];
    const float* v = (const float*)d_in[2];
    const int* topk = (const int*)d_in[3];
    float* out = (float*)d_out;

    double* part   = (double*)d_ws;                        // 512 KB, fully written by k1
    double* scores = (double*)((char*)d_ws + 524288);      // 2 MiB, fully written by k2

    k_reduce_q<<<BB * CHUNKS_Q, 256, 0, stream>>>(q, part, out);
    k_scores<<<BB * (LL / 256), 256, 0, stream>>>(k, part, scores, out);
    k_select_gather<<<BB, 1024, 0, stream>>>(scores, topk, v, out);
}